// Round 4
// baseline (1607.846 us; speedup 1.0000x reference)
//
#include <hip/hip_runtime.h>

#define N_NODES 100000
#define N_EDGES 600000
#define IN_DIM 128
#define EDGE_DIM 32
#define HIDDEN 128
#define NBLK 391  // ceil(N_NODES/256)

typedef __attribute__((ext_vector_type(8))) short bf16x8;
typedef __attribute__((ext_vector_type(4))) float f32x4;

__device__ inline unsigned short f2bf(float f) {
    unsigned int u = __float_as_uint(f);
    unsigned int r = (u + 0x7FFF + ((u >> 16) & 1)) >> 16;  // RNE
    return (unsigned short)r;
}

// ===========================================================================
// CSR build
// ===========================================================================
__global__ void hist_kernel(const int* __restrict__ dst, int* __restrict__ cnt) {
    int e = blockIdx.x * blockDim.x + threadIdx.x;
    if (e < N_EDGES) atomicAdd(&cnt[dst[e]], 1);
}

__global__ void scan1_kernel(const int* __restrict__ cnt,
                             int* __restrict__ scanout, int* __restrict__ bsum) {
    __shared__ int s[256];
    int tid = threadIdx.x;
    int i = blockIdx.x * 256 + tid;
    int v = (i < N_NODES) ? cnt[i] : 0;
    s[tid] = v;
    __syncthreads();
#pragma unroll
    for (int off = 1; off < 256; off <<= 1) {
        int t = 0;
        if (tid >= off) t = s[tid - off];
        __syncthreads();
        if (tid >= off) s[tid] += t;
        __syncthreads();
    }
    if (i < N_NODES) scanout[i] = s[tid];
    if (tid == 255) bsum[blockIdx.x] = s[255];
}

__global__ void scan2_kernel(int* __restrict__ bsum) {
    __shared__ int s[512];
    int tid = threadIdx.x;
    int v = (tid < NBLK) ? bsum[tid] : 0;
    s[tid] = v;
    __syncthreads();
#pragma unroll
    for (int off = 1; off < 512; off <<= 1) {
        int t = 0;
        if (tid >= off) t = s[tid - off];
        __syncthreads();
        if (tid >= off) s[tid] += t;
        __syncthreads();
    }
    if (tid < NBLK) bsum[tid] = s[tid] - v;  // exclusive
}

__global__ void scan3_kernel(const int* __restrict__ cnt,
                             const int* __restrict__ scanout,
                             const int* __restrict__ bsum,
                             int* __restrict__ rowptr, int* __restrict__ cur) {
    int i = blockIdx.x * 256 + threadIdx.x;
    if (i < N_NODES) {
        int excl = scanout[i] + bsum[i >> 8] - cnt[i];
        rowptr[i] = excl;
        cur[i] = excl;
    }
    if (i == 0) rowptr[N_NODES] = N_EDGES;
}

// pk[pos] = { src | (dst&31)<<27 , original edge id }
__global__ void fill_kernel(const int* __restrict__ src, const int* __restrict__ dst,
                            int* __restrict__ cur, int2* __restrict__ pk) {
    int e = blockIdx.x * blockDim.x + threadIdx.x;
    if (e < N_EDGES) {
        int d = dst[e];
        int pos = atomicAdd(&cur[d], 1);
        int2 v;
        v.x = src[e] | ((d & 31) << 27);
        v.y = e;
        pk[pos] = v;
    }
}

// ===========================================================================
// eam[n][32] = mean of ea rows over incoming edges (graph-invariant, once).
// block = 32 nodes; 256 threads = 8 edges x 32 feats; LDS fp32 atomics.
// ===========================================================================
__global__ __launch_bounds__(256) void eam_kernel(const int* __restrict__ rowptr,
                                                  const int2* __restrict__ pk,
                                                  const float* __restrict__ ea,
                                                  float* __restrict__ eam) {
    __shared__ float s[32][EDGE_DIM];
    __shared__ int s_rp[33];
    int t = threadIdx.x;
    int n0 = blockIdx.x * 32;
    if (t <= 32) s_rp[t] = rowptr[n0 + t];
    for (int i = t; i < 32 * EDGE_DIM; i += 256) ((float*)s)[i] = 0.f;
    __syncthreads();

    int E0 = s_rp[0], E1 = s_rp[32];
    int eg = t >> 5, k = t & 31;
    int pos = E0 + eg;
    for (; pos + 8 < E1; pos += 16) {
        int2 a0 = pk[pos];
        int2 a1 = pk[pos + 8];
        float v0 = ea[a0.y * EDGE_DIM + k];
        float v1 = ea[a1.y * EDGE_DIM + k];
        int ln0 = (unsigned)a0.x >> 27;
        int ln1 = (unsigned)a1.x >> 27;
        atomicAdd(&s[ln0][k], v0);
        atomicAdd(&s[ln1][k], v1);
    }
    if (pos < E1) {
        int2 a0 = pk[pos];
        float v0 = ea[a0.y * EDGE_DIM + k];
        atomicAdd(&s[(unsigned)a0.x >> 27][k], v0);
    }
    __syncthreads();

    for (int i = t; i < 32 * EDGE_DIM; i += 256) {
        int ln = i >> 5;
        int c = s_rp[ln + 1] - s_rp[ln];
        eam[n0 * EDGE_DIM + i] = ((float*)s)[i] / (float)(c > 0 ? c : 1);
    }
}

// ===========================================================================
// WeWl = We @ Wl (32x128), beWl = be @ Wl (128)
// ===========================================================================
__global__ void wewl_kernel(const float* __restrict__ We, const float* __restrict__ be,
                            const float* __restrict__ Wl,
                            float* __restrict__ WeWl, float* __restrict__ beWl) {
    int idx = blockIdx.x * 256 + threadIdx.x;
    if (idx >= 33 * 128) return;
    int r = idx >> 7;
    int n = idx & 127;
    float s = 0.f;
    if (r < 32) {
        for (int j = 0; j < 128; ++j) s += We[r * 128 + j] * Wl[j * 128 + n];
        WeWl[r * 128 + n] = s;
    } else {
        for (int j = 0; j < 128; ++j) s += be[j] * Wl[j * 128 + n];
        beWl[n] = s;
    }
}

// ===========================================================================
// Fused SAGE layer. 16 nodes/block (N_NODES = 16*6250).
// Phase 1: edge-parallel x gather-sum into LDS (fp32 atomics), 8 edges x
//          32 float4-lanes per step, 2x unrolled (2 gathers in flight).
// Phase 2: K=288 register-tiled fp32 GEMM (8 nodes x 1 feat per thread).
// out[i] = relu(mean_x@Wl + eam@WeWl + 1{d>0}beWl + bl + x@Wr + br)
// ===========================================================================
__global__ __launch_bounds__(256) void sage_layer_kernel(
        const float* __restrict__ xin,
        const int* __restrict__ rowptr,
        const int2* __restrict__ pk,
        const float* __restrict__ eam,
        const float* __restrict__ WeWl,
        const float* __restrict__ beWl,
        const float* __restrict__ Wl,
        const float* __restrict__ bl,
        const float* __restrict__ Wr,
        const float* __restrict__ br,
        float* __restrict__ out) {
    __shared__ float s_mean[16][HIDDEN];
    __shared__ float s_x[16][HIDDEN];
    __shared__ float s_eam[16][EDGE_DIM];
    __shared__ int s_info[17];

    int t = threadIdx.x;
    int n0 = blockIdx.x * 16;

    if (t <= 16) s_info[t] = rowptr[n0 + t];
    for (int i = t; i < 16 * HIDDEN; i += 256) {
        ((float*)s_mean)[i] = 0.f;
        ((float*)s_x)[i] = xin[n0 * HIDDEN + i];      // contiguous block rows
    }
    for (int i = t; i < 16 * EDGE_DIM; i += 256)
        ((float*)s_eam)[i] = eam[n0 * EDGE_DIM + i];  // precomputed mean(ea)
    __syncthreads();

    // ---- edge-parallel x gather ----
    int E0 = s_info[0], E1 = s_info[16];
    int eg = t >> 5, k4 = (t & 31) * 4;
    int pos = E0 + eg;
    for (; pos + 8 < E1; pos += 16) {
        int a0 = pk[pos].x;
        int a1 = pk[pos + 8].x;
        int sn0 = a0 & 131071;
        int sn1 = a1 & 131071;
        float4 v0 = *(const float4*)&xin[sn0 * HIDDEN + k4];
        float4 v1 = *(const float4*)&xin[sn1 * HIDDEN + k4];
        int ln0 = ((unsigned)a0 >> 27) & 15;
        int ln1 = ((unsigned)a1 >> 27) & 15;
        atomicAdd(&s_mean[ln0][k4 + 0], v0.x);
        atomicAdd(&s_mean[ln0][k4 + 1], v0.y);
        atomicAdd(&s_mean[ln0][k4 + 2], v0.z);
        atomicAdd(&s_mean[ln0][k4 + 3], v0.w);
        atomicAdd(&s_mean[ln1][k4 + 0], v1.x);
        atomicAdd(&s_mean[ln1][k4 + 1], v1.y);
        atomicAdd(&s_mean[ln1][k4 + 2], v1.z);
        atomicAdd(&s_mean[ln1][k4 + 3], v1.w);
    }
    if (pos < E1) {
        int a0 = pk[pos].x;
        int sn0 = a0 & 131071;
        float4 v0 = *(const float4*)&xin[sn0 * HIDDEN + k4];
        int ln0 = ((unsigned)a0 >> 27) & 15;
        atomicAdd(&s_mean[ln0][k4 + 0], v0.x);
        atomicAdd(&s_mean[ln0][k4 + 1], v0.y);
        atomicAdd(&s_mean[ln0][k4 + 2], v0.z);
        atomicAdd(&s_mean[ln0][k4 + 3], v0.w);
    }
    __syncthreads();

    // ---- scale to mean ----
    for (int i = t; i < 16 * HIDDEN; i += 256) {
        int ln = i >> 7;
        int c = s_info[ln + 1] - s_info[ln];
        ((float*)s_mean)[i] /= (float)(c > 0 ? c : 1);
    }
    __syncthreads();

    // ---- GEMM: 8 nodes x 1 feature per thread, K = 128+128+32 ----
    int f = t & 127;
    int g = t >> 7;
    int nb = g * 8;

    float bias = bl[f] + br[f];
    float bw = beWl[f];
    float acc[8];
#pragma unroll
    for (int j = 0; j < 8; ++j) {
        int c = s_info[nb + j + 1] - s_info[nb + j];
        acc[j] = bias + (c > 0 ? bw : 0.f);
    }

    for (int k = 0; k < HIDDEN; k += 4) {
        float wl0 = Wl[(k + 0) * HIDDEN + f];
        float wl1 = Wl[(k + 1) * HIDDEN + f];
        float wl2 = Wl[(k + 2) * HIDDEN + f];
        float wl3 = Wl[(k + 3) * HIDDEN + f];
        float wr0 = Wr[(k + 0) * HIDDEN + f];
        float wr1 = Wr[(k + 1) * HIDDEN + f];
        float wr2 = Wr[(k + 2) * HIDDEN + f];
        float wr3 = Wr[(k + 3) * HIDDEN + f];
#pragma unroll
        for (int j = 0; j < 8; ++j) {
            float4 m = *(const float4*)&s_mean[nb + j][k];
            float4 xx = *(const float4*)&s_x[nb + j][k];
            acc[j] += m.x * wl0 + m.y * wl1 + m.z * wl2 + m.w * wl3
                    + xx.x * wr0 + xx.y * wr1 + xx.z * wr2 + xx.w * wr3;
        }
    }
#pragma unroll
    for (int k = 0; k < EDGE_DIM; k += 4) {
        float w0 = WeWl[(k + 0) * HIDDEN + f];
        float w1 = WeWl[(k + 1) * HIDDEN + f];
        float w2 = WeWl[(k + 2) * HIDDEN + f];
        float w3 = WeWl[(k + 3) * HIDDEN + f];
#pragma unroll
        for (int j = 0; j < 8; ++j) {
            float4 e4 = *(const float4*)&s_eam[nb + j][k];
            acc[j] += e4.x * w0 + e4.y * w1 + e4.z * w2 + e4.w * w3;
        }
    }

#pragma unroll
    for (int j = 0; j < 8; ++j) {
        float v = acc[j];
        out[(n0 + nb + j) * HIDDEN + f] = v > 0.f ? v : 0.f;
    }
}

// ===========================================================================
// Wp1 bf16 fragment swizzle + edge MLP via MFMA (unchanged from R2)
// ===========================================================================
__global__ void wp1_swizzle_kernel(const float* __restrict__ Wp1,
                                   unsigned short* __restrict__ Wp1s) {
    int idx = blockIdx.x * blockDim.x + threadIdx.x;  // 32768 total
    int j = idx & 7;
    int lane = (idx >> 3) & 63;
    int ks = (idx >> 9) & 7;
    int nt = (idx >> 12) & 7;
    int k = ks * 32 + ((lane >> 4) & 3) * 8 + j;
    int n = nt * 16 + (lane & 15);
    Wp1s[idx] = f2bf(Wp1[k * HIDDEN + n]);
}

#define HE_PITCH 264
__global__ __launch_bounds__(256) void edge_mlp_mfma_kernel(
        const float* __restrict__ h,
        const int* __restrict__ src,
        const int* __restrict__ dst,
        const unsigned short* __restrict__ Wp1s,
        const float* __restrict__ bp1,
        const float* __restrict__ Wp2,
        const float* __restrict__ bp2,
        float* __restrict__ out) {
    __shared__ unsigned short s_he[64 * HE_PITCH];

    int t = threadIdx.x;
    int e0 = blockIdx.x * 64;

    int lane32 = t & 31;
    int hr0 = t >> 5;
    for (int hr = hr0; hr < 128; hr += 8) {
        int e = e0 + (hr >> 1);
        int node = (hr & 1) ? dst[e] : src[e];
        float4 v = *(const float4*)&h[node * HIDDEN + lane32 * 4];
        ushort4 w;
        w.x = f2bf(v.x); w.y = f2bf(v.y); w.z = f2bf(v.z); w.w = f2bf(v.w);
        *(ushort4*)&s_he[(hr >> 1) * HE_PITCH + (hr & 1) * 128 + lane32 * 4] = w;
    }
    __syncthreads();

    int wave = t >> 6;
    int lane = t & 63;
    int col = lane & 15;
    int kgrp = lane >> 4;

    f32x4 acc[8];
#pragma unroll
    for (int nt = 0; nt < 8; ++nt) acc[nt] = (f32x4){0.f, 0.f, 0.f, 0.f};

    const bf16x8* __restrict__ Wb = (const bf16x8*)Wp1s;
    const unsigned abase = (wave * 16 + col) * HE_PITCH + kgrp * 8;

#pragma unroll
    for (int ks = 0; ks < 8; ++ks) {
        bf16x8 afrag = *(const bf16x8*)&s_he[abase + ks * 32];
#pragma unroll
        for (int nt = 0; nt < 8; ++nt) {
            bf16x8 bfrag = Wb[(nt * 8 + ks) * 64 + lane];
            acc[nt] = __builtin_amdgcn_mfma_f32_16x16x32_bf16(afrag, bfrag, acc[nt], 0, 0, 0);
        }
    }

    float z[8][4];
#pragma unroll
    for (int nt = 0; nt < 8; ++nt) {
        float b = bp1[nt * 16 + col];
#pragma unroll
        for (int r = 0; r < 4; ++r) {
            float v = acc[nt][r] + b;
            z[nt][r] = v > 0.f ? v : 0.f;
        }
    }

    float w2c0[8], w2c1[8];
#pragma unroll
    for (int nt = 0; nt < 8; ++nt) {
        int n = nt * 16 + col;
        w2c0[nt] = Wp2[n * 2 + 0];
        w2c1[nt] = Wp2[n * 2 + 1];
    }
    float p0[4], p1[4];
#pragma unroll
    for (int r = 0; r < 4; ++r) {
        float a0 = 0.f, a1 = 0.f;
#pragma unroll
        for (int nt = 0; nt < 8; ++nt) {
            a0 += z[nt][r] * w2c0[nt];
            a1 += z[nt][r] * w2c1[nt];
        }
        p0[r] = a0; p1[r] = a1;
    }
#pragma unroll
    for (int m = 8; m >= 1; m >>= 1) {
#pragma unroll
        for (int r = 0; r < 4; ++r) {
            p0[r] += __shfl_xor(p0[r], m);
            p1[r] += __shfl_xor(p1[r], m);
        }
    }
    if (col < 2) {
        float bias = bp2[col];
#pragma unroll
        for (int r = 0; r < 4; ++r) {
            int e = e0 + wave * 16 + kgrp * 4 + r;
            out[e * 2 + col] = (col == 0 ? p0[r] : p1[r]) + bias;
        }
    }
}

// ===========================================================================
extern "C" void kernel_launch(void* const* d_in, const int* in_sizes, int n_in,
                              void* d_out, int out_size, void* d_ws, size_t ws_size,
                              hipStream_t stream) {
    const float* x   = (const float*)d_in[0];
    const int*   ei  = (const int*)d_in[1];
    const float* ea  = (const float*)d_in[2];
    const float* We1 = (const float*)d_in[3];
    const float* be1 = (const float*)d_in[4];
    const float* Wl1 = (const float*)d_in[5];
    const float* bl1 = (const float*)d_in[6];
    const float* Wr1 = (const float*)d_in[7];
    const float* br1 = (const float*)d_in[8];
    const float* We2 = (const float*)d_in[9];
    const float* be2 = (const float*)d_in[10];
    const float* Wl2 = (const float*)d_in[11];
    const float* bl2 = (const float*)d_in[12];
    const float* Wr2 = (const float*)d_in[13];
    const float* br2 = (const float*)d_in[14];
    const float* Wp1 = (const float*)d_in[15];
    const float* bp1 = (const float*)d_in[16];
    const float* Wp2 = (const float*)d_in[17];
    const float* bp2 = (const float*)d_in[18];
    float* out = (float*)d_out;

    const int* src = ei;
    const int* dst = ei + N_EDGES;

    char* ws = (char*)d_ws;
    int*   cnt     = (int*)(ws + 0);
    int*   scanout = (int*)(ws + 409600);
    int*   bsum    = (int*)(ws + 819200);
    int*   rowptr  = (int*)(ws + 827392);
    int*   cur     = (int*)(ws + 1236992);
    int2*  pk      = (int2*)(ws + 1646592);            // 4.8 MB
    float* WeWl1   = (float*)(ws + 6446592);
    float* beWl1   = (float*)(ws + 6462976);
    float* WeWl2   = (float*)(ws + 6463488);
    float* beWl2   = (float*)(ws + 6479872);
    float* eam     = (float*)(ws + 6480384);           // 12.8 MB
    float* h1      = (float*)(ws + 19280384);          // 51.2 MB
    float* h2      = (float*)(ws + 70480384);          // 51.2 MB
    unsigned short* Wp1s = (unsigned short*)(ws + 121680384);

    const int EB = (N_EDGES + 255) / 256;

    // ---- CSR build ----
    hipMemsetAsync(cnt, 0, N_NODES * sizeof(int), stream);
    hist_kernel<<<EB, 256, 0, stream>>>(dst, cnt);
    scan1_kernel<<<NBLK, 256, 0, stream>>>(cnt, scanout, bsum);
    scan2_kernel<<<1, 512, 0, stream>>>(bsum);
    scan3_kernel<<<NBLK, 256, 0, stream>>>(cnt, scanout, bsum, rowptr, cur);
    fill_kernel<<<EB, 256, 0, stream>>>(src, dst, cur, pk);

    // ---- graph-invariant precompute ----
    eam_kernel<<<N_NODES / 32, 256, 0, stream>>>(rowptr, pk, ea, eam);
    wewl_kernel<<<17, 256, 0, stream>>>(We1, be1, Wl1, WeWl1, beWl1);
    wewl_kernel<<<17, 256, 0, stream>>>(We2, be2, Wl2, WeWl2, beWl2);
    wp1_swizzle_kernel<<<32768 / 256, 256, 0, stream>>>(Wp1, Wp1s);

    // ---- layers ----
    sage_layer_kernel<<<N_NODES / 16, 256, 0, stream>>>(
        x, rowptr, pk, eam, WeWl1, beWl1, Wl1, bl1, Wr1, br1, h1);
    sage_layer_kernel<<<N_NODES / 16, 256, 0, stream>>>(
        h1, rowptr, pk, eam, WeWl2, beWl2, Wl2, bl2, Wr2, br2, h2);

    // ---- edge predictor (MFMA) ----
    edge_mlp_mfma_kernel<<<N_EDGES / 64, 256, 0, stream>>>(
        h2, src, dst, Wp1s, bp1, Wp2, bp2, out);
}